// Round 12
// baseline (146.677 us; speedup 1.0000x reference)
//
#include <hip/hip_runtime.h>

#define SS 384
#define BB 2
#define DD 256
#define NPART 1024
#define SLAB4 (SS * SS / 4)   // 36864 float4 per (b,i) slab

#define ZBLKS 1152            // stage1: zero-sweep blocks (write lower-tri zeros)
#define WBLKS 1024            // stage1: W partial-sum blocks
#define RBLKS 576             // stage1: row-sum blocks

typedef float f32x4 __attribute__((ext_vector_type(4)));

// ws float layout:
//  [16..16+1024)  W partial sums
//  [2048..2816)   m1 row sums  (b*S+i)
//  [2816..3584)   m2 row sums
//  [3584..4352)   m3 row sums (raw)
#define WS_PART 16
#define WS_M1 2048
#define WS_M2 2816
#define WS_M3 3584

// --- stage 1 (2752 blocks): three concurrent jobs.
//  blocks [0,1152): write the statically-zero lower-triangle float4s (227 MB of
//    pure CONSTANT stores - the fill-shaped 7 TB/s path) - hides the W read.
//  blocks [1152,2176): deterministic W partial sums (67 MB read).
//  blocks [2176,2752): row sums of m1/m2/m3.
__global__ void __launch_bounds__(256) stage1_kernel(const float* __restrict__ m1,
                                                     const float* __restrict__ m2,
                                                     const float* __restrict__ m3,
                                                     const float* __restrict__ W,
                                                     float* __restrict__ ws,
                                                     float* __restrict__ out) {
    int bx = blockIdx.x;
    int t  = threadIdx.x;
    if (bx < ZBLKS) {
        // zero-sweep: thread owns fixed (j,k4) slot in an 8-slab frontier.
        unsigned g     = (unsigned)bx * 256u + (unsigned)t;   // 0..294911
        unsigned which = g / SLAB4;                           // 0..7
        unsigned so    = g - which * SLAB4;
        int j  = (int)(so / 96);
        int k4 = (int)(so - (unsigned)j * 96);
        if (k4 * 4 + 3 <= j) {            // float4 is entirely below/on diagonal
            f32x4 z = {0.f, 0.f, 0.f, 0.f};
            f32x4* dst = (f32x4*)out + so + (size_t)which * SLAB4;
            #pragma unroll 8
            for (int bi = (int)which; bi < BB * SS; bi += 8) {
                *dst = z;                 // constant store, no input deps
                dst += 8 * SLAB4;
            }
        }
    } else if (bx < ZBLKS + WBLKS) {
        // deterministic per-block partial sums of W (16.7M floats)
        __shared__ float sm[4];
        int wb = bx - ZBLKS;
        const f32x4* W4 = (const f32x4*)W;
        const unsigned n4 = (DD * DD * DD) / 4;  // 4194304
        float s = 0.f;
        for (unsigned i = (unsigned)wb * 256u + t; i < n4; i += WBLKS * 256) {
            f32x4 v = W4[i];
            s += (v.x + v.y) + (v.z + v.w);
        }
        #pragma unroll
        for (int off = 32; off; off >>= 1) s += __shfl_down(s, off, 64);
        int lane = t & 63, w = t >> 6;
        if (lane == 0) sm[w] = s;
        __syncthreads();
        if (t == 0) ws[WS_PART + wb] = (sm[0] + sm[1]) + (sm[2] + sm[3]);
    } else {
        // row sums: one wave per row, D=256 -> float4/lane
        int wave = (bx - ZBLKS - WBLKS) * 4 + (t >> 6);
        int lane = t & 63;
        if (wave >= 3 * BB * SS) return;
        const float* src;
        float* dst;
        if (wave < BB * SS)          { src = m1 + (size_t)wave * DD;                 dst = ws + WS_M1 + wave; }
        else if (wave < 2 * BB * SS) { src = m2 + (size_t)(wave - BB * SS) * DD;     dst = ws + WS_M2 + (wave - BB * SS); }
        else                         { src = m3 + (size_t)(wave - 2 * BB * SS) * DD; dst = ws + WS_M3 + (wave - 2 * BB * SS); }
        f32x4 v = ((const f32x4*)src)[lane];
        float s = (v.x + v.y) + (v.z + v.w);
        #pragma unroll
        for (int off = 32; off; off >>= 1) s += __shfl_down(s, off, 64);
        if (lane == 0) *dst = s;
    }
}

// --- writer (2304 blocks x 256): nonzero-containing float4s only (~226 MB).
// Sweep geometry: thread owns fixed (j,k4) in a 16-slab frontier, walks
// bi += 16 (48 steps). Threads whose float4 is fully zero (4k4+3 <= j) exit
// after the prologue - stage1 already wrote those. Store loop: chunked
// {12 broadcast ds_reads -> 12 dependency-free cached stores}.
__global__ void __launch_bounds__(256) writer_kernel(const float* __restrict__ ws,
                                                     float* __restrict__ out) {
    __shared__ float sred[8];
    __shared__ float c1l[BB * SS];    // m1 row sums * Wtot/16
    int t = threadIdx.x;

    // block-reduce the 1024 W-partials (deterministic fixed order)
    const float* p = ws + WS_PART;
    float s = (p[t] + p[t + 256]) + (p[t + 512] + p[t + 768]);
    #pragma unroll
    for (int off = 32; off; off >>= 1) s += __shfl_down(s, off, 64);
    int lane = t & 63, w = t >> 6;
    if (lane == 0) sred[w] = s;
    __syncthreads();
    if (t == 0) sred[4] = (((sred[0] + sred[1]) + (sred[2] + sred[3]))) * (1.0f / 16.0f);
    __syncthreads();
    float wt16 = sred[4];             // Wtot / SCALE, SCALE = sqrt(768/3) = 16

    // stage scaled m1 row sums to LDS
    c1l[t]       = ws[WS_M1 + t]       * wt16;
    c1l[t + 256] = ws[WS_M1 + t + 256] * wt16;
    c1l[t + 512] = ws[WS_M1 + t + 512] * wt16;
    __syncthreads();

    unsigned g     = blockIdx.x * 256u + (unsigned)t;  // 0..589823
    unsigned which = g / SLAB4;                        // 0..15
    unsigned so    = g - which * SLAB4;
    int j  = (int)(so / 96);
    int k4 = (int)(so - (unsigned)j * 96);
    int k0 = k4 * 4;
    if (k0 + 3 <= j) return;          // fully-zero float4: stage1 wrote it

    // per-thread constants (prologue vmem loads only)
    f32x4 fa = ((const f32x4*)(ws + WS_M3))[k4];        // b=0 m3 sums
    f32x4 fb = ((const f32x4*)(ws + WS_M3 + SS))[k4];   // b=1
    f32x4 fm0, fm1;
    fm0.x = (k0 + 0 > j) ? fa.x : 0.f;
    fm0.y = (k0 + 1 > j) ? fa.y : 0.f;
    fm0.z = (k0 + 2 > j) ? fa.z : 0.f;
    fm0.w = (k0 + 3 > j) ? fa.w : 0.f;
    fm1.x = (k0 + 0 > j) ? fb.x : 0.f;
    fm1.y = (k0 + 1 > j) ? fb.y : 0.f;
    fm1.z = (k0 + 2 > j) ? fb.z : 0.f;
    fm1.w = (k0 + 3 > j) ? fb.w : 0.f;
    float m2v0 = ws[WS_M2 + j];
    float m2v1 = ws[WS_M2 + SS + j];

    // 4 chunks x {12 ds_reads -> 12 stores}; b boundary at step 24 (chunk 2)
    const float* c1p = c1l + which;           // bi = which + step*16
    f32x4* dst = (f32x4*)out + so + (size_t)which * SLAB4;
    #pragma unroll
    for (int ch = 0; ch < 4; ++ch) {
        float m2v = (ch < 2) ? m2v0 : m2v1;
        f32x4 fm  = (ch < 2) ? fm0 : fm1;
        float cj[12];
        #pragma unroll
        for (int q = 0; q < 12; ++q)
            cj[q] = c1p[(ch * 12 + q) * 16] * m2v;   // broadcast ds_read, static offset
        #pragma unroll
        for (int q = 0; q < 12; ++q) {
            f32x4 o;
            o.x = cj[q] * fm.x;
            o.y = cj[q] * fm.y;
            o.z = cj[q] * fm.z;
            o.w = cj[q] * fm.w;
            dst[(size_t)(ch * 12 + q) * 16 * SLAB4] = o;  // dependency-free burst
        }
    }
}

extern "C" void kernel_launch(void* const* d_in, const int* in_sizes, int n_in,
                              void* d_out, int out_size, void* d_ws, size_t ws_size,
                              hipStream_t stream) {
    const float* m1 = (const float*)d_in[0];
    const float* m2 = (const float*)d_in[1];
    const float* m3 = (const float*)d_in[2];
    const float* W  = (const float*)d_in[3];
    float* out = (float*)d_out;
    float* ws  = (float*)d_ws;

    // stage1: zero lower-triangle (227 MB const stores) || W partials || row sums
    stage1_kernel<<<ZBLKS + WBLKS + RBLKS, 256, 0, stream>>>(m1, m2, m3, W, ws, out);
    // writer: nonzero float4s only (~226 MB)
    writer_kernel<<<2304, 256, 0, stream>>>(ws, out);
}

// Round 13
// 103.137 us; speedup vs baseline: 1.4222x; 1.4222x over previous
//
#include <hip/hip_runtime.h>

#define SS 384
#define BB 2
#define DD 256
#define NPART 1024
#define SLAB4 (SS * SS / 4)   // 36864 float4 per (b,i) slab

typedef float f32x4 __attribute__((ext_vector_type(4)));

// ws float layout:
//  [16..16+1024)  W partial sums
//  [2048..2816)   m1 row sums  (b*S+i)
//  [2816..3584)   m2 row sums
//  [3584..4352)   m3 row sums (raw)
#define WS_PART 16
#define WS_M1 2048
#define WS_M2 2816
#define WS_M3 3584

// --- fused stage 1: blocks [0,NPART) do W partial sums; blocks [NPART, NPART+576) do row sums
__global__ void stage1_kernel(const float* __restrict__ m1,
                              const float* __restrict__ m2,
                              const float* __restrict__ m3,
                              const float* __restrict__ W,
                              float* __restrict__ ws) {
    if (blockIdx.x < NPART) {
        __shared__ float sm[4];
        const f32x4* W4 = (const f32x4*)W;
        const unsigned n4 = (DD * DD * DD) / 4;  // 4194304
        float s = 0.f;
        for (unsigned i = blockIdx.x * blockDim.x + threadIdx.x; i < n4; i += NPART * 256) {
            f32x4 v = W4[i];
            s += (v.x + v.y) + (v.z + v.w);
        }
        #pragma unroll
        for (int off = 32; off; off >>= 1) s += __shfl_down(s, off, 64);
        int lane = threadIdx.x & 63, w = threadIdx.x >> 6;
        if (lane == 0) sm[w] = s;
        __syncthreads();
        if (threadIdx.x == 0) ws[WS_PART + blockIdx.x] = (sm[0] + sm[1]) + (sm[2] + sm[3]);
    } else {
        // row sums: one wave per row, D=256 -> float4/lane
        int wave = (int)(blockIdx.x - NPART) * 4 + (int)(threadIdx.x >> 6);
        int lane = threadIdx.x & 63;
        if (wave >= 3 * BB * SS) return;
        const float* src;
        float* dst;
        if (wave < BB * SS)          { src = m1 + (size_t)wave * DD;                 dst = ws + WS_M1 + wave; }
        else if (wave < 2 * BB * SS) { src = m2 + (size_t)(wave - BB * SS) * DD;     dst = ws + WS_M2 + (wave - BB * SS); }
        else                         { src = m3 + (size_t)(wave - 2 * BB * SS) * DD; dst = ws + WS_M3 + (wave - 2 * BB * SS); }
        f32x4 v = ((const f32x4*)src)[lane];
        float s = (v.x + v.y) + (v.z + v.w);
        #pragma unroll
        for (int off = 32; off; off >>= 1) s += __shfl_down(s, off, 64);
        if (lane == 0) *dst = s;
    }
}

// --- writer: lockstep sweep + register-staged store bursts (R11 best: 102.3us).
// 1152 blocks x 256 thr = 294912 threads = 8 slabs of frontier; thread owns a
// fixed (j,k4) slot, walks bi += 8 (96 steps) in 6 chunks of 16:
// phase A = 16 broadcast ds_reads -> cj regs, phase B = 16 dependency-free
// cached stores. Measured ledger: NT 4.78, in-loop-load 4.7, sweep 5.57
// (REPS=5, WRITE_SIZE-verified), fill 6.9-7.1 TB/s. Contiguous full-line
// wave store footprint is mandatory (R12: fragmenting it cost +44us).
__global__ void __launch_bounds__(256) writer_kernel(const float* __restrict__ ws,
                                                     float* __restrict__ out) {
    __shared__ float sred[8];
    __shared__ float c1l[BB * SS];    // m1 row sums * Wtot/16
    int t = threadIdx.x;

    // block-reduce the 1024 W-partials (deterministic fixed order)
    const float* p = ws + WS_PART;
    float s = (p[t] + p[t + 256]) + (p[t + 512] + p[t + 768]);
    #pragma unroll
    for (int off = 32; off; off >>= 1) s += __shfl_down(s, off, 64);
    int lane = t & 63, w = t >> 6;
    if (lane == 0) sred[w] = s;
    __syncthreads();
    if (t == 0) sred[4] = (((sred[0] + sred[1]) + (sred[2] + sred[3]))) * (1.0f / 16.0f);
    __syncthreads();
    float wt16 = sred[4];             // Wtot / SCALE, SCALE = sqrt(768/3) = 16

    // stage scaled m1 row sums to LDS
    c1l[t]       = ws[WS_M1 + t]       * wt16;
    c1l[t + 256] = ws[WS_M1 + t + 256] * wt16;
    c1l[t + 512] = ws[WS_M1 + t + 512] * wt16;

    unsigned g     = blockIdx.x * 256u + t;   // 0..294911
    unsigned which = g / SLAB4;               // 0..7 (slab position in frontier)
    unsigned so    = g - which * SLAB4;       // slot in slab (float4)
    int j  = (int)(so / 96);
    int k4 = (int)(so - (unsigned)j * 96);
    int k0 = k4 * 4;

    // per-thread constants (prologue vmem loads only)
    f32x4 fa = ((const f32x4*)(ws + WS_M3))[k4];        // b=0 m3 sums
    f32x4 fb = ((const f32x4*)(ws + WS_M3 + SS))[k4];   // b=1
    f32x4 fm0, fm1;
    fm0.x = (k0 + 0 > j) ? fa.x : 0.f;
    fm0.y = (k0 + 1 > j) ? fa.y : 0.f;
    fm0.z = (k0 + 2 > j) ? fa.z : 0.f;
    fm0.w = (k0 + 3 > j) ? fa.w : 0.f;
    fm1.x = (k0 + 0 > j) ? fb.x : 0.f;
    fm1.y = (k0 + 1 > j) ? fb.y : 0.f;
    fm1.z = (k0 + 2 > j) ? fb.z : 0.f;
    fm1.w = (k0 + 3 > j) ? fb.w : 0.f;
    float m2v0 = ws[WS_M2 + j];
    float m2v1 = ws[WS_M2 + SS + j];
    __syncthreads();

    // fully-static chunked store loop: 6 chunks x {16 ds_reads -> 16 stores}
    const float* c1p = c1l + which;           // bi = which + step*8
    f32x4* dst = (f32x4*)out + so + (size_t)which * SLAB4;
    #pragma unroll
    for (int ch = 0; ch < 6; ++ch) {
        float m2v = (ch < 3) ? m2v0 : m2v1;   // b boundary at step 48 (chunk 3)
        f32x4 fm  = (ch < 3) ? fm0 : fm1;
        float cj[16];
        #pragma unroll
        for (int q = 0; q < 16; ++q)
            cj[q] = c1p[(ch * 16 + q) * 8] * m2v;   // broadcast ds_read, static offset
        #pragma unroll
        for (int q = 0; q < 16; ++q) {
            f32x4 o;
            o.x = cj[q] * fm.x;
            o.y = cj[q] * fm.y;
            o.z = cj[q] * fm.z;
            o.w = cj[q] * fm.w;
            dst[(size_t)(ch * 16 + q) * 8 * SLAB4] = o;  // dependency-free burst
        }
    }
}

extern "C" void kernel_launch(void* const* d_in, const int* in_sizes, int n_in,
                              void* d_out, int out_size, void* d_ws, size_t ws_size,
                              hipStream_t stream) {
    const float* m1 = (const float*)d_in[0];
    const float* m2 = (const float*)d_in[1];
    const float* m3 = (const float*)d_in[2];
    const float* W  = (const float*)d_in[3];
    float* out = (float*)d_out;
    float* ws  = (float*)d_ws;

    // fused: W partial sums (1024 blocks) + all row sums (576 blocks)
    stage1_kernel<<<NPART + 576, 256, 0, stream>>>(m1, m2, m3, W, ws);
    // masked outer-product write (443 MB), register-staged store bursts
    writer_kernel<<<1152, 256, 0, stream>>>(ws, out);
}